// Round 11
// baseline (61.235 us; speedup 1.0000x reference)
//
#include <hip/hip_runtime.h>

typedef __attribute__((ext_vector_type(8))) short short8;
typedef __attribute__((ext_vector_type(4))) float f32x4;
typedef __attribute__((ext_vector_type(16))) float f32x16;

// ---------------- ws layout (bytes) ----------------
// rcp  : float [8][512]                        @ 0         (16384)
// wpre : bf16  [c=8][t=9][kb=8][co=512][8]     @ 16384     (4718592)
// xm   : bf16  [b=8][g=64][hp=34][col=34][8]   @ 4734976   (9469952)  (hp=0 / hp=33 are zero rows)
#define RCP_OFF   0
#define WPRE_OFF  16384
#define XM_OFF    4734976

__device__ __forceinline__ unsigned short f2bf(float f) {
  unsigned int u = __float_as_uint(f);
  u += 0x7FFFu + ((u >> 16) & 1u);       // round-to-nearest-even
  return (unsigned short)(u >> 16);
}

__device__ __forceinline__ void gload_lds16(const void* g, void* l) {
  __builtin_amdgcn_global_load_lds(
      (__attribute__((address_space(1))) void*)g,
      (__attribute__((address_space(3))) void*)l, 16, 0, 0);
}

// ---------------- fused prep: xm (blocks 0-511) | wpre (512-639) | xs (640-767) ----------------
__global__ __launch_bounds__(256) void prep_kernel(
    const float* __restrict__ x, const float* __restrict__ ys,
    const float* __restrict__ w,
    unsigned short* __restrict__ xm, unsigned short* __restrict__ wpre,
    float* __restrict__ rcp) {
  int bid = blockIdx.x;
  int tid = threadIdx.x;

  if (bid < 512) {
    // ---- xm: modulated x -> bf16, channel-grouped, padded h & w ----
    int half = bid & 1;
    int h = (bid >> 1) & 31;
    int b = bid >> 6;
    __shared__ float tile[256][33];
    int ci0 = half * 256;
#pragma unroll
    for (int r = 0; r < 32; ++r) {
      int ci = r * 8 + (tid >> 5);
      int wcol = tid & 31;
      float v = x[(((size_t)b * 512 + ci0 + ci) * 32 + h) * 32 + wcol];
      tile[ci][wcol] = v * ys[b * 512 + ci0 + ci];
    }
    __syncthreads();
    int g0 = half * 32;
    for (int r = 0; r < 5; ++r) {
      int idx = r * 256 + tid;                     // [gl(32)][col(34)]
      if (idx < 1088) {
        int gl = idx / 34;
        int col = idx - gl * 34;
        short8 v = {0,0,0,0,0,0,0,0};
        if (col != 0 && col != 33) {
          int wcol = col - 1;
#pragma unroll
          for (int j = 0; j < 8; ++j)
            v[j] = (short)f2bf(tile[gl * 8 + j][wcol]);
        }
        size_t off = ((((size_t)b * 64 + g0 + gl) * 34 + (h + 1)) * 34 + col) * 8;
        *reinterpret_cast<short8*>(xm + off) = v;
      }
    }
    if (h == 0 || h == 31) {
      int hp = (h == 0) ? 0 : 33;
      for (int r = 0; r < 5; ++r) {
        int idx = r * 256 + tid;
        if (idx < 1088) {
          int gl = idx / 34;
          int col = idx - gl * 34;
          short8 z = {0,0,0,0,0,0,0,0};
          size_t off = ((((size_t)b * 64 + g0 + gl) * 34 + hp) * 34 + col) * 8;
          *reinterpret_cast<short8*>(xm + off) = z;
        }
      }
    }
  } else if (bid < 640) {
    // ---- wpre: scaled weight -> bf16 fragment layout ----
    int pid = bid - 512;             // [c(8)][kb(8)][coh(2)]
    int coh = pid & 1;
    int kb = (pid >> 1) & 7;
    int c = pid >> 4;
    int co = coh * 256 + tid;
    int ci0 = c * 64 + kb * 8;
    const float* wp = w + (size_t)co * 4608 + (size_t)ci0 * 9;   // 72 contiguous floats
    float v[72];
    const f32x4* wp4 = reinterpret_cast<const f32x4*>(wp);
#pragma unroll
    for (int i = 0; i < 18; ++i) {
      f32x4 q = wp4[i];
      v[i * 4 + 0] = q[0]; v[i * 4 + 1] = q[1]; v[i * 4 + 2] = q[2]; v[i * 4 + 3] = q[3];
    }
    const float scale = 1.4731391274719738e-02f;   // (512*9)^-0.5
#pragma unroll
    for (int t = 0; t < 9; ++t) {
      short8 s;
#pragma unroll
      for (int j = 0; j < 8; ++j) s[j] = (short)f2bf(scale * v[j * 9 + t]);
      *reinterpret_cast<short8*>(wpre + ((((size_t)c * 9 + t) * 8 + kb) * 512 + co) * 8) = s;
    }
  } else {
    // ---- xs: demod rcp[b][o], one wave per o ----
    int pid = bid - 640;
    int wv = tid >> 6;
    int lane = tid & 63;
    int o = pid * 4 + wv;
    const float* wp = w + (size_t)o * 4608 + (size_t)lane * 72;  // 8 ci x 9 taps
    const float scale2 = 1.0f / 4608.0f;
    float w2[8];
#pragma unroll
    for (int j = 0; j < 8; ++j) {
      float s = 0.f;
#pragma unroll
      for (int k = 0; k < 9; ++k) { float vv = wp[j * 9 + k]; s += vv * vv; }
      w2[j] = s * scale2;
    }
#pragma unroll
    for (int b = 0; b < 8; ++b) {
      float p = 0.f;
#pragma unroll
      for (int j = 0; j < 8; ++j) {
        float y = ys[b * 512 + lane * 8 + j];
        p += y * y * w2[j];
      }
#pragma unroll
      for (int off = 32; off > 0; off >>= 1) p += __shfl_down(p, off);
      if (lane == 0) rcp[b * 512 + o] = 1.0f / sqrtf(p + 1e-8f);
    }
  }
}

// ---------------- main: implicit-GEMM direct conv, 32x32x16 MFMA + tap-phase schedule ----------------
// grid 256 (XCD-pinned cog), block 512 = 8 waves (wc = h-pair, wr = co-half, kp = K-split).
// R10 change: 16x16x32 -> 32x32x16 MFMA (gfx950 µbench 2495 vs 2075 TF = +20% rate,
// and 8 instead of 16 MFMA per tap per wave at identical A/B bytes).
// Fragment layouts (family pattern, C/D guide-verified m74/m101):
//   A: m=lane&31 (co), k=8*(lane>>5)+j ; B: n=lane&31 (px-w), same k ;
//   C/D: col=lane&31, row=(reg&3)+8*(reg>>2)+4*(lane>>5).
// Wave tile: 2(mi co-32) x 2(nj h-row) tiles, ks 2 K-steps (kb pairs), K=32/tap/wave.
// Phase schedule per tap (R9, the proven win): issue A(ct+2) -> s_barrier (align,
// no drain) -> lgkmcnt(0) -> sched_barrier(0) -> issue B(t+1) -> setprio(1) ->
// 8 MFMA -> setprio(0). Counted vmcnt(8) only at chunk boundaries.
__global__ __launch_bounds__(512, 1) void conv_main(
    const unsigned short* __restrict__ wpre,
    const unsigned short* __restrict__ xm,
    const float* __restrict__ rcp,
    const float* __restrict__ bias,
    float* __restrict__ out)
{
  __shared__ __align__(16) char smem[52224];

  int bid = blockIdx.x;
  int xcd = bid & 7;
  int j0 = bid >> 3;                // 0..31 within XCD
  int cog = xcd >> 1;               // 2 XCDs per cog
  int sp = (xcd & 1) * 32 + j0;
  int b = sp >> 3;
  int hg = sp & 7;
  int tid = threadIdx.x;
  int lane = tid & 63;
  int wv = tid >> 6;                // 0..7
  int wc = wv & 1;                  // h-pair within the 4-row block tile
  int wr = (wv >> 1) & 1;           // co 64-half
  int kp = wv >> 2;                 // K-split half (kb 0-3 / 4-7)
  int l31 = lane & 31, l5 = lane >> 5;

  f32x16 acc[2][2];
#pragma unroll
  for (int i = 0; i < 2; ++i)
#pragma unroll
    for (int jj = 0; jj < 2; ++jj) acc[i][jj] = (f32x16)(0.f);

  const unsigned short* xmb = xm + (size_t)b * (64 * 34 * 34 * 8);
  // A-frag lane base: (kb = kp*4 + l5, co = cog*128 + wr*64 + l31); +ks*8192 +mi*256 elems
  const unsigned short* wbase =
      wpre + ((size_t)(kp * 4 + l5) * 512 + cog * 128 + wr * 64 + l31) * 8;
  // B-frag lane base byte addr in xbuf; + ks*6528 + (nj+kh)*544 + kw*16
  const int bbase = (kp * 4 + l5) * 3264 + wc * 2 * 544 + l31 * 16;

  auto stageX = [&](int c, int buf) {
    char* xb = smem + buf * 26112;
#pragma unroll
    for (int r = 0; r < 4; ++r) {
      int idx = r * 512 + tid;                 // [kb(8)][rr(6)][col(34)] = 1632 chunks
      if (idx < 1632) {
        int kb = idx / 204;
        int rem = idx - kb * 204;
        int rr = rem / 34;
        int col = rem - rr * 34;
        const unsigned short* src =
            xmb + (((size_t)(c * 8 + kb) * 34 + hg * 4 + rr) * 34 + col) * 8;
        gload_lds16(src, xb + idx * 16);
      }
    }
  };

  auto loadA = [&](int ct, short8 (&a)[4]) {   // a[ks*2+mi]
    const unsigned short* p = wbase + (size_t)ct * 32768;
#pragma unroll
    for (int ks = 0; ks < 2; ++ks)
#pragma unroll
      for (int mi = 0; mi < 2; ++mi)
        a[ks * 2 + mi] = *reinterpret_cast<const short8*>(p + ks * 8192 + mi * 256);
  };

  auto loadB = [&](const char* xb, int t, short8 (&f)[4]) {   // f[ks*2+nj]
    int kh = t / 3, kw = t % 3;              // compile-time (t unrolled)
#pragma unroll
    for (int ks = 0; ks < 2; ++ks)
#pragma unroll
      for (int nj = 0; nj < 2; ++nj) {
        int imm = ks * 6528 + (nj + kh) * 544 + kw * 16;
        f[ks * 2 + nj] = *reinterpret_cast<const short8*>(xb + bbase + imm);
      }
  };

  short8 X[4], Y[4], Z[4];          // depth-2 A pipeline, roles rotate t%3 (9%3==0)

  // prologue
  stageX(0, 0);
  loadA(0, X);
  loadA(1, Y);
  asm volatile("s_waitcnt vmcnt(8)" ::: "memory");   // stageX(0) done; A-loads fly
  __builtin_amdgcn_s_barrier();
  asm volatile("" ::: "memory");

  for (int c = 0; c < 8; ++c) {
    const char* xb = smem + (c & 1) * 26112;
    if (c < 7) stageX(c + 1, (c + 1) & 1);   // async; drains at chunk-end barrier
    short8 Bp[4], Bq[4];                     // cross-tap B reg dbuf (chunk-local)
    loadB(xb, 0, Bp);                        // one exposed B latency per chunk
#pragma unroll
    for (int t = 0; t < 9; ++t) {
      int ct = c * 9 + t;
      short8 (&curA)[4] = (t % 3 == 0) ? X : ((t % 3 == 1) ? Y : Z);   // static
      short8 (&nxtA)[4] = (t % 3 == 0) ? Z : ((t % 3 == 1) ? X : Y);   // (t+2)%3
      short8 (&curB)[4] = (t & 1) ? Bq : Bp;
      short8 (&nxtB)[4] = (t & 1) ? Bp : Bq;
      if (ct < 70) loadA(ct + 2, nxtA);      // depth-2 global prefetch (stays in flight)
      __builtin_amdgcn_s_barrier();          // phase-align the 8 waves (no drain)
      asm volatile("s_waitcnt lgkmcnt(0)" ::: "memory");
      __builtin_amdgcn_sched_barrier(0);     // rule #18: MFMA must not hoist past wait
      if (t < 8) loadB(xb, t + 1, nxtB);     // issue B(t+1); hides under MFMA cluster
      __builtin_amdgcn_s_setprio(1);
#pragma unroll
      for (int ks = 0; ks < 2; ++ks)
#pragma unroll
        for (int nj = 0; nj < 2; ++nj)
#pragma unroll
          for (int mi = 0; mi < 2; ++mi)
            acc[mi][nj] = __builtin_amdgcn_mfma_f32_32x32x16_bf16(
                curA[ks * 2 + mi], curB[ks * 2 + nj], acc[mi][nj], 0, 0, 0);
      __builtin_amdgcn_s_setprio(0);
    }
    if (c < 7) {
      // counted drain: stageX(c+1) done; 8 newest vmem (A prefetches) in flight.
      asm volatile("s_waitcnt vmcnt(8) lgkmcnt(0)" ::: "memory");
      __builtin_amdgcn_s_barrier();
      asm volatile("" ::: "memory");
    }
  }
  __syncthreads();                  // full drain before smem reuse

  // ---- K-split reduction (kp1 -> LDS -> kp0), 2 phases over wr ----
#pragma unroll
  for (int p = 0; p < 2; ++p) {
    if (kp == 1 && wr == p) {
#pragma unroll
      for (int mi = 0; mi < 2; ++mi)
#pragma unroll
        for (int nj = 0; nj < 2; ++nj)
          *reinterpret_cast<f32x16*>(smem + wc * 16384 + (mi * 2 + nj) * 4096 + lane * 64) = acc[mi][nj];
    }
    __syncthreads();
    if (kp == 0 && wr == p) {
#pragma unroll
      for (int mi = 0; mi < 2; ++mi)
#pragma unroll
        for (int nj = 0; nj < 2; ++nj) {
          f32x16 v = *reinterpret_cast<const f32x16*>(smem + wc * 16384 + (mi * 2 + nj) * 4096 + lane * 64);
          acc[mi][nj] = acc[mi][nj] + v;
        }
    }
    __syncthreads();
  }

  // ---- epilogue: demod + bias, fp32 NCHW store ----
  // C/D: col(lane&31)=w, row=(reg&3)+8*(reg>>2)+4*(lane>>5) = co offset within 32-tile
  if (kp == 0) {
    const float* rcpb = rcp + b * 512;
#pragma unroll
    for (int mi = 0; mi < 2; ++mi) {
#pragma unroll
      for (int g = 0; g < 4; ++g) {          // reg>>2
        int cb = cog * 128 + wr * 64 + mi * 32 + g * 8 + l5 * 4;
        f32x4 rc = *reinterpret_cast<const f32x4*>(rcpb + cb);
        f32x4 bi = *reinterpret_cast<const f32x4*>(bias + cb);
#pragma unroll
        for (int nj = 0; nj < 2; ++nj) {
          int h = hg * 4 + wc * 2 + nj;
#pragma unroll
          for (int r = 0; r < 4; ++r) {      // reg&3
            int reg = g * 4 + r;
            out[(((size_t)b * 512 + cb + r) * 32 + h) * 32 + l31] =
                acc[mi][nj][reg] * rc[r] + bi[r];
          }
        }
      }
    }
  }
}

extern "C" void kernel_launch(void* const* d_in, const int* in_sizes, int n_in,
                              void* d_out, int out_size, void* d_ws, size_t ws_size,
                              hipStream_t stream) {
  const float* x    = (const float*)d_in[0];
  const float* ys   = (const float*)d_in[1];
  const float* w    = (const float*)d_in[2];
  const float* bias = (const float*)d_in[3];
  float* out = (float*)d_out;
  char* ws = (char*)d_ws;
  float* rcp = (float*)(ws + RCP_OFF);
  unsigned short* wpre = (unsigned short*)(ws + WPRE_OFF);
  unsigned short* xm   = (unsigned short*)(ws + XM_OFF);

  prep_kernel<<<768, 256, 0, stream>>>(x, ys, w, xm, wpre, rcp);
  conv_main<<<256, 512, 0, stream>>>(wpre, xm, rcp, bias, out);
}

// Round 12
// 59.334 us; speedup vs baseline: 1.0320x; 1.0320x over previous
//
#include <hip/hip_runtime.h>

typedef __attribute__((ext_vector_type(8))) short short8;
typedef __attribute__((ext_vector_type(4))) float f32x4;

// ---------------- ws layout (bytes) ----------------
// rcp  : float [8][512]                        @ 0         (16384)
// wpre : bf16  [c=8][t=9][kb=8][co=512][8]     @ 16384     (4718592)
#define RCP_OFF   0
#define WPRE_OFF  16384

__device__ __forceinline__ unsigned short f2bf(float f) {
  unsigned int u = __float_as_uint(f);
  u += 0x7FFFu + ((u >> 16) & 1u);       // round-to-nearest-even
  return (unsigned short)(u >> 16);
}

// ---------------- prep: wpre (blocks 0-127) | xs (128-255) ----------------
__global__ __launch_bounds__(256) void prep_kernel(
    const float* __restrict__ ys, const float* __restrict__ w,
    unsigned short* __restrict__ wpre, float* __restrict__ rcp) {
  int bid = blockIdx.x;
  int tid = threadIdx.x;

  if (bid < 128) {
    // ---- wpre: scaled weight -> bf16 fragment layout ----
    int pid = bid;                   // [c(8)][kb(8)][coh(2)]
    int coh = pid & 1;
    int kb = (pid >> 1) & 7;
    int c = pid >> 4;
    int co = coh * 256 + tid;
    int ci0 = c * 64 + kb * 8;
    const float* wp = w + (size_t)co * 4608 + (size_t)ci0 * 9;   // 72 contiguous floats
    float v[72];
    const f32x4* wp4 = reinterpret_cast<const f32x4*>(wp);
#pragma unroll
    for (int i = 0; i < 18; ++i) {
      f32x4 q = wp4[i];
      v[i * 4 + 0] = q[0]; v[i * 4 + 1] = q[1]; v[i * 4 + 2] = q[2]; v[i * 4 + 3] = q[3];
    }
    const float scale = 1.4731391274719738e-02f;   // (512*9)^-0.5
#pragma unroll
    for (int t = 0; t < 9; ++t) {
      short8 s;
#pragma unroll
      for (int j = 0; j < 8; ++j) s[j] = (short)f2bf(scale * v[j * 9 + t]);
      *reinterpret_cast<short8*>(wpre + ((((size_t)c * 9 + t) * 8 + kb) * 512 + co) * 8) = s;
    }
  } else {
    // ---- xs: demod rcp[b][o], one wave per o ----
    int pid = bid - 128;
    int wv = tid >> 6;
    int lane = tid & 63;
    int o = pid * 4 + wv;
    const float* wp = w + (size_t)o * 4608 + (size_t)lane * 72;  // 8 ci x 9 taps
    const float scale2 = 1.0f / 4608.0f;
    float w2[8];
#pragma unroll
    for (int j = 0; j < 8; ++j) {
      float s = 0.f;
#pragma unroll
      for (int k = 0; k < 9; ++k) { float vv = wp[j * 9 + k]; s += vv * vv; }
      w2[j] = s * scale2;
    }
#pragma unroll
    for (int b = 0; b < 8; ++b) {
      float p = 0.f;
#pragma unroll
      for (int j = 0; j < 8; ++j) {
        float y = ys[b * 512 + lane * 8 + j];
        p += y * y * w2[j];
      }
#pragma unroll
      for (int off = 32; off > 0; off >>= 1) p += __shfl_down(p, off);
      if (lane == 0) rcp[b * 512 + o] = 1.0f / sqrtf(p + 1e-8f);
    }
  }
}

// ---------------- main: implicit-GEMM direct conv, fused modulation staging ----------------
// grid 256 (XCD-pinned cog), block 512 = 8 waves (wc,wr 2x2 spatial, kp K-split).
// 16x16x32 MFMA (R11's 32x32 regressed: 4 accs at dep-distance 4 stalls the pipe;
// 16 accs at distance 16 does not). R9 tap-phase schedule kept verbatim.
// R12 change: xm intermediate ELIMINATED. Staging is reg-staged x (T14 split):
//   chunk start: issue 32x 4B x-loads + 8x f32x4 ys (oldest in VMEM queue)
//   chunk end:   vmcnt(8) [x arrived; 8 newest = A prefetches stay in flight]
//                -> cvt x*ys -> bf16 (VALU was 88% idle) -> ds_write_b128 to the
//                buffer the NEXT chunk reads -> lgkmcnt(0) -> s_barrier.
// Halo rows / pad cols: clamped addresses + zero mask at staging time.
__global__ __launch_bounds__(512, 1) void conv_main(
    const unsigned short* __restrict__ wpre,
    const float* __restrict__ x,
    const float* __restrict__ ys,
    const float* __restrict__ rcp,
    const float* __restrict__ bias,
    float* __restrict__ out)
{
  __shared__ __align__(16) char smem[52224];

  int bid = blockIdx.x;
  int xcd = bid & 7;
  int j0 = bid >> 3;                // 0..31 within XCD
  int cog = xcd >> 1;               // 2 XCDs per cog
  int sp = (xcd & 1) * 32 + j0;
  int b = sp >> 3;
  int hg = sp & 7;
  int tid = threadIdx.x;
  int lane = tid & 63;
  int wv = tid >> 6;                // 0..7
  int wc = wv & 1;
  int wr = (wv >> 1) & 1;
  int kp = wv >> 2;                 // K-split half
  int l15 = lane & 15, l4 = lane >> 4;

  f32x4 acc[4][4];
#pragma unroll
  for (int i = 0; i < 4; ++i)
#pragma unroll
    for (int jj = 0; jj < 4; ++jj) { f32x4 z = {0.f,0.f,0.f,0.f}; acc[i][jj] = z; }

  const unsigned short* wbase =
      wpre + ((size_t)(kp * 4 + l4) * 512 + cog * 128 + wr * 64 + l15) * 8;
  const int bbase = (kp * 4 + l4) * 3264 + wc * 2 * 544 + l15 * 16;

  // ---- per-thread staging geometry (chunk-independent; all static-indexed) ----
  // idx in [0,1632): [kb(8)][rr(6)][col(34)]; LDS byte = idx*16 (16B = 8 ci bf16)
  const float* xB = x + (size_t)b * 524288;        // b*512*1024
  const float* yB = ys + b * 512;
  int xoff_[4], ysoff_[4], ldsoff_[4];
  bool act_[4], val_[4];
#pragma unroll
  for (int p = 0; p < 4; ++p) {
    int idx = p * 512 + tid;
    act_[p] = idx < 1632;
    int kb = idx / 204;
    int rem = idx - kb * 204;
    int rr = rem / 34;
    int col = rem - rr * 34;
    int hr = hg * 4 - 1 + rr;
    val_[p] = act_[p] && col >= 1 && col <= 32 && hr >= 0 && hr <= 31;
    int hrc = min(max(hr, 0), 31);
    int wcc = min(max(col - 1, 0), 31);
    xoff_[p] = (kb * 8 * 32 + hrc) * 32 + wcc;     // + c*65536
    ysoff_[p] = kb * 8;                            // + c*64
    ldsoff_[p] = idx * 16;
  }

  float  xr[4][8];                  // staged x values (live across the tap loop)
  f32x4  yr[4][2];                  // staged ys values

  auto issueX = [&](int c) {        // issue x+ys loads for chunk c (oldest in queue)
#pragma unroll
    for (int p = 0; p < 4; ++p) {
      if (act_[p]) {
        const float* xp = xB + c * 65536 + xoff_[p];
        yr[p][0] = *reinterpret_cast<const f32x4*>(yB + c * 64 + ysoff_[p]);
        yr[p][1] = *reinterpret_cast<const f32x4*>(yB + c * 64 + ysoff_[p] + 4);
#pragma unroll
        for (int j = 0; j < 8; ++j) xr[p][j] = xp[j * 1024];
      }
    }
  };

  auto writeX = [&](int buf) {      // cvt + ds_write (call after vmcnt drained x)
    char* xb = smem + buf * 26112;
#pragma unroll
    for (int p = 0; p < 4; ++p) {
      if (act_[p]) {
        short8 v = {0,0,0,0,0,0,0,0};
        if (val_[p]) {
#pragma unroll
          for (int j = 0; j < 8; ++j) {
            float yj = (j < 4) ? yr[p][0][j] : yr[p][1][j - 4];
            v[j] = (short)f2bf(xr[p][j] * yj);
          }
        }
        *reinterpret_cast<short8*>(xb + ldsoff_[p]) = v;
      }
    }
  };

  auto loadA = [&](int ct, short8 (&a)[4]) {
    const unsigned short* p = wbase + (size_t)ct * 32768;
#pragma unroll
    for (int mi = 0; mi < 4; ++mi)
      a[mi] = *reinterpret_cast<const short8*>(p + mi * 128);
  };

  auto loadB = [&](const char* xb, int t, short8 (&f)[4]) {
    int kh = t / 3, kw = t % 3;              // compile-time (t unrolled)
#pragma unroll
    for (int nj = 0; nj < 4; ++nj) {
      int imm = ((nj >> 1) + kh) * 544 + (nj & 1) * 256 + kw * 16;
      f[nj] = *reinterpret_cast<const short8*>(xb + bbase + imm);
    }
  };

  short8 X[4], Y[4], Z[4];          // depth-2 A pipeline, roles rotate t%3 (9%3==0)

  // prologue: stage chunk 0
  issueX(0);
  loadA(0, X);
  loadA(1, Y);
  asm volatile("s_waitcnt vmcnt(8)" ::: "memory");   // x/ys done; A-loads fly
  writeX(0);
  asm volatile("s_waitcnt lgkmcnt(0)" ::: "memory");
  __builtin_amdgcn_s_barrier();
  asm volatile("" ::: "memory");

  for (int c = 0; c < 8; ++c) {
    const char* xb = smem + (c & 1) * 26112;
    if (c < 7) issueX(c + 1);                // x+ys loads fly under the 9 tap phases
    short8 Bp[4], Bq[4];                     // cross-tap B reg dbuf (chunk-local)
    loadB(xb, 0, Bp);                        // one exposed B latency per chunk
#pragma unroll
    for (int t = 0; t < 9; ++t) {
      int ct = c * 9 + t;
      short8 (&curA)[4] = (t % 3 == 0) ? X : ((t % 3 == 1) ? Y : Z);   // static
      short8 (&nxtA)[4] = (t % 3 == 0) ? Z : ((t % 3 == 1) ? X : Y);   // (t+2)%3
      short8 (&curB)[4] = (t & 1) ? Bq : Bp;
      short8 (&nxtB)[4] = (t & 1) ? Bp : Bq;
      if (ct < 70) loadA(ct + 2, nxtA);      // depth-2 global prefetch (stays in flight)
      __builtin_amdgcn_s_barrier();          // phase-align the 8 waves (no drain)
      asm volatile("s_waitcnt lgkmcnt(0)" ::: "memory");
      __builtin_amdgcn_sched_barrier(0);     // rule #18: MFMA must not hoist past wait
      if (t < 8) loadB(xb, t + 1, nxtB);     // issue B(t+1); hides under MFMA cluster
      __builtin_amdgcn_s_setprio(1);
#pragma unroll
      for (int nj = 0; nj < 4; ++nj)
#pragma unroll
        for (int mi = 0; mi < 4; ++mi)
          acc[mi][nj] = __builtin_amdgcn_mfma_f32_16x16x32_bf16(curA[mi], curB[nj], acc[mi][nj], 0, 0, 0);
      __builtin_amdgcn_s_setprio(0);
    }
    if (c < 7) {
      // x/ys (oldest) drained; 8 newest vmem (A prefetches for next chunk's
      // taps 0,1) stay in flight. Then cvt+write into the buffer next chunk reads.
      asm volatile("s_waitcnt vmcnt(8)" ::: "memory");
      writeX((c + 1) & 1);
      asm volatile("s_waitcnt lgkmcnt(0)" ::: "memory");
      __builtin_amdgcn_s_barrier();
      asm volatile("" ::: "memory");
    }
  }
  __syncthreads();                  // full drain before smem reuse

  // ---- K-split reduction (kp1 -> LDS -> kp0) ----
#pragma unroll
  for (int p = 0; p < 2; ++p) {
    if (kp == 1 && wr == p) {
#pragma unroll
      for (int mi = 0; mi < 4; ++mi)
#pragma unroll
        for (int nj = 0; nj < 4; ++nj)
          *reinterpret_cast<f32x4*>(smem + wc * 16384 + (mi * 4 + nj) * 1024 + lane * 16) = acc[mi][nj];
    }
    __syncthreads();
    if (kp == 0 && wr == p) {
#pragma unroll
      for (int mi = 0; mi < 4; ++mi)
#pragma unroll
        for (int nj = 0; nj < 4; ++nj) {
          f32x4 v = *reinterpret_cast<const f32x4*>(smem + wc * 16384 + (mi * 4 + nj) * 1024 + lane * 16);
          acc[mi][nj] = acc[mi][nj] + v;
        }
    }
    __syncthreads();
  }

  // ---- epilogue: demod + bias, fp32 NCHW store ----
  if (kp == 0) {
    const float* rcpb = rcp + b * 512;
#pragma unroll
    for (int mi = 0; mi < 4; ++mi) {
      int ob = cog * 128 + wr * 64 + mi * 16 + l4 * 4;
      float rc[4], bi[4];
#pragma unroll
      for (int jj = 0; jj < 4; ++jj) { rc[jj] = rcpb[ob + jj]; bi[jj] = bias[ob + jj]; }
#pragma unroll
      for (int nj = 0; nj < 4; ++nj) {
        int row4 = wc * 2 + (nj >> 1);
        int wcol = (nj & 1) * 16 + l15;
        int h = hg * 4 + row4;
#pragma unroll
        for (int jj = 0; jj < 4; ++jj)
          out[(((size_t)b * 512 + ob + jj) * 32 + h) * 32 + wcol] = acc[mi][nj][jj] * rc[jj] + bi[jj];
      }
    }
  }
}

extern "C" void kernel_launch(void* const* d_in, const int* in_sizes, int n_in,
                              void* d_out, int out_size, void* d_ws, size_t ws_size,
                              hipStream_t stream) {
  const float* x    = (const float*)d_in[0];
  const float* ys   = (const float*)d_in[1];
  const float* w    = (const float*)d_in[2];
  const float* bias = (const float*)d_in[3];
  float* out = (float*)d_out;
  char* ws = (char*)d_ws;
  float* rcp = (float*)(ws + RCP_OFF);
  unsigned short* wpre = (unsigned short*)(ws + WPRE_OFF);

  prep_kernel<<<256, 256, 0, stream>>>(ys, w, wpre, rcp);
  conv_main<<<256, 512, 0, stream>>>(wpre, x, ys, rcp, bias, out);
}

// Round 13
// 55.028 us; speedup vs baseline: 1.1128x; 1.0782x over previous
//
#include <hip/hip_runtime.h>

typedef __attribute__((ext_vector_type(8))) short short8;
typedef __attribute__((ext_vector_type(4))) float f32x4;

// ---------------- ws layout (bytes) ----------------
// rcp  : float [8][512]                        @ 0         (16384)
// wpre : bf16  [c=8][t=9][kb=8][co=512][8]     @ 16384     (4718592)
// xm   : bf16  [b=8][g=64][hp=34][col=34][8]   @ 4734976   (9469952)  (hp=0 / hp=33 are zero rows)
#define RCP_OFF   0
#define WPRE_OFF  16384
#define XM_OFF    4734976

__device__ __forceinline__ unsigned short f2bf(float f) {
  unsigned int u = __float_as_uint(f);
  u += 0x7FFFu + ((u >> 16) & 1u);       // round-to-nearest-even
  return (unsigned short)(u >> 16);
}

__device__ __forceinline__ void gload_lds16(const void* g, void* l) {
  __builtin_amdgcn_global_load_lds(
      (__attribute__((address_space(1))) void*)g,
      (__attribute__((address_space(3))) void*)l, 16, 0, 0);
}

// ---------------- fused prep: xm (blocks 0-511) | wpre (512-639) | xs (640-767) ----------------
__global__ __launch_bounds__(256) void prep_kernel(
    const float* __restrict__ x, const float* __restrict__ ys,
    const float* __restrict__ w,
    unsigned short* __restrict__ xm, unsigned short* __restrict__ wpre,
    float* __restrict__ rcp) {
  int bid = blockIdx.x;
  int tid = threadIdx.x;

  if (bid < 512) {
    // ---- xm: modulated x -> bf16, channel-grouped, padded h & w ----
    int half = bid & 1;
    int h = (bid >> 1) & 31;
    int b = bid >> 6;
    __shared__ float tile[256][33];
    int ci0 = half * 256;
#pragma unroll
    for (int r = 0; r < 32; ++r) {
      int ci = r * 8 + (tid >> 5);
      int wcol = tid & 31;
      float v = x[(((size_t)b * 512 + ci0 + ci) * 32 + h) * 32 + wcol];
      tile[ci][wcol] = v * ys[b * 512 + ci0 + ci];
    }
    __syncthreads();
    int g0 = half * 32;
    for (int r = 0; r < 5; ++r) {
      int idx = r * 256 + tid;                     // [gl(32)][col(34)]
      if (idx < 1088) {
        int gl = idx / 34;
        int col = idx - gl * 34;
        short8 v = {0,0,0,0,0,0,0,0};
        if (col != 0 && col != 33) {
          int wcol = col - 1;
#pragma unroll
          for (int j = 0; j < 8; ++j)
            v[j] = (short)f2bf(tile[gl * 8 + j][wcol]);
        }
        size_t off = ((((size_t)b * 64 + g0 + gl) * 34 + (h + 1)) * 34 + col) * 8;
        *reinterpret_cast<short8*>(xm + off) = v;
      }
    }
    if (h == 0 || h == 31) {
      int hp = (h == 0) ? 0 : 33;
      for (int r = 0; r < 5; ++r) {
        int idx = r * 256 + tid;
        if (idx < 1088) {
          int gl = idx / 34;
          int col = idx - gl * 34;
          short8 z = {0,0,0,0,0,0,0,0};
          size_t off = ((((size_t)b * 64 + g0 + gl) * 34 + hp) * 34 + col) * 8;
          *reinterpret_cast<short8*>(xm + off) = z;
        }
      }
    }
  } else if (bid < 640) {
    // ---- wpre: scaled weight -> bf16 fragment layout ----
    int pid = bid - 512;             // [c(8)][kb(8)][coh(2)]
    int coh = pid & 1;
    int kb = (pid >> 1) & 7;
    int c = pid >> 4;
    int co = coh * 256 + tid;
    int ci0 = c * 64 + kb * 8;
    const float* wp = w + (size_t)co * 4608 + (size_t)ci0 * 9;   // 72 contiguous floats
    float v[72];
    const f32x4* wp4 = reinterpret_cast<const f32x4*>(wp);
#pragma unroll
    for (int i = 0; i < 18; ++i) {
      f32x4 q = wp4[i];
      v[i * 4 + 0] = q[0]; v[i * 4 + 1] = q[1]; v[i * 4 + 2] = q[2]; v[i * 4 + 3] = q[3];
    }
    const float scale = 1.4731391274719738e-02f;   // (512*9)^-0.5
#pragma unroll
    for (int t = 0; t < 9; ++t) {
      short8 s;
#pragma unroll
      for (int j = 0; j < 8; ++j) s[j] = (short)f2bf(scale * v[j * 9 + t]);
      *reinterpret_cast<short8*>(wpre + ((((size_t)c * 9 + t) * 8 + kb) * 512 + co) * 8) = s;
    }
  } else {
    // ---- xs: demod rcp[b][o], one wave per o ----
    int pid = bid - 640;
    int wv = tid >> 6;
    int lane = tid & 63;
    int o = pid * 4 + wv;
    const float* wp = w + (size_t)o * 4608 + (size_t)lane * 72;  // 8 ci x 9 taps
    const float scale2 = 1.0f / 4608.0f;
    float w2[8];
#pragma unroll
    for (int j = 0; j < 8; ++j) {
      float s = 0.f;
#pragma unroll
      for (int k = 0; k < 9; ++k) { float vv = wp[j * 9 + k]; s += vv * vv; }
      w2[j] = s * scale2;
    }
#pragma unroll
    for (int b = 0; b < 8; ++b) {
      float p = 0.f;
#pragma unroll
      for (int j = 0; j < 8; ++j) {
        float y = ys[b * 512 + lane * 8 + j];
        p += y * y * w2[j];
      }
#pragma unroll
      for (int off = 32; off > 0; off >>= 1) p += __shfl_down(p, off);
      if (lane == 0) rcp[b * 512 + o] = 1.0f / sqrtf(p + 1e-8f);
    }
  }
}

// ---------------- main: implicit-GEMM direct conv, tap-phase schedule ----------------
// grid 256 (XCD-pinned cog), block 512 = 8 waves (wc,wr 2x2 spatial, kp K-split).
// = R10 (best known) with ONE change: stageX(c+1) is issued MID-CHUNK (after
// tap 4's A-prefetch) instead of at chunk start. Rationale: vmcnt is FIFO, and
// the compiler's counted wait on curA before each MFMA cluster also forces all
// OLDER loads complete — with stage issued first, taps 0-1 of every chunk
// stalled on the next chunk's L3-latency staging (~1-2k cyc x 8 chunks). With
// stage issued after tap 4's A(t+2), no MFMA cluster waits on stage loads, and
// stage still has ~4 taps (~5.5k cyc) to land before the chunk-end vmcnt(8).
// Stage addresses precomputed per-thread (no divides in the hot phase).
__global__ __launch_bounds__(512, 1) void conv_main(
    const unsigned short* __restrict__ wpre,
    const unsigned short* __restrict__ xm,
    const float* __restrict__ rcp,
    const float* __restrict__ bias,
    float* __restrict__ out)
{
  __shared__ __align__(16) char smem[52224];

  int bid = blockIdx.x;
  int xcd = bid & 7;
  int j0 = bid >> 3;                // 0..31 within XCD
  int cog = xcd >> 1;               // 2 XCDs per cog
  int sp = (xcd & 1) * 32 + j0;
  int b = sp >> 3;
  int hg = sp & 7;
  int tid = threadIdx.x;
  int lane = tid & 63;
  int wv = tid >> 6;                // 0..7
  int wc = wv & 1;
  int wr = (wv >> 1) & 1;
  int kp = wv >> 2;                 // K-split half
  int l15 = lane & 15, l4 = lane >> 4;

  f32x4 acc[4][4];
#pragma unroll
  for (int i = 0; i < 4; ++i)
#pragma unroll
    for (int jj = 0; jj < 4; ++jj) { f32x4 z = {0.f,0.f,0.f,0.f}; acc[i][jj] = z; }

  const unsigned short* xmb = xm + (size_t)b * (64 * 34 * 34 * 8);
  const unsigned short* wbase =
      wpre + ((size_t)(kp * 4 + l4) * 512 + cog * 128 + wr * 64 + l15) * 8;
  const int bbase = (kp * 4 + l4) * 3264 + wc * 2 * 544 + l15 * 16;

  // ---- precomputed staging geometry: idx = [kb(8)][rr(6)][col(34)] = 1632 ----
  // xm elem offset within chunk slab = ((kb*34 + hg*4+rr)*34 + col)*8 ; +c*73984
  int soff_[4], sld_[4];
  bool sact_[4];
#pragma unroll
  for (int p = 0; p < 4; ++p) {
    int idx = p * 512 + tid;
    sact_[p] = idx < 1632;
    int kb = idx / 204;
    int rem = idx - kb * 204;
    int rr = rem / 34;
    int col = rem - rr * 34;
    soff_[p] = ((kb * 34 + hg * 4 + rr) * 34 + col) * 8;
    sld_[p] = idx * 16;
  }

  auto stageX = [&](int c, int buf) {
    char* xb = smem + buf * 26112;
    const unsigned short* base = xmb + (size_t)c * 73984;
#pragma unroll
    for (int p = 0; p < 4; ++p)
      if (sact_[p]) gload_lds16(base + soff_[p], xb + sld_[p]);
  };

  auto loadA = [&](int ct, short8 (&a)[4]) {
    const unsigned short* p = wbase + (size_t)ct * 32768;
#pragma unroll
    for (int mi = 0; mi < 4; ++mi)
      a[mi] = *reinterpret_cast<const short8*>(p + mi * 128);
  };

  auto loadB = [&](const char* xb, int t, short8 (&f)[4]) {
    int kh = t / 3, kw = t % 3;              // compile-time (t unrolled)
#pragma unroll
    for (int nj = 0; nj < 4; ++nj) {
      int imm = ((nj >> 1) + kh) * 544 + (nj & 1) * 256 + kw * 16;
      f[nj] = *reinterpret_cast<const short8*>(xb + bbase + imm);
    }
  };

  short8 X[4], Y[4], Z[4];          // depth-2 A pipeline, roles rotate t%3 (9%3==0)

  // prologue
  stageX(0, 0);
  loadA(0, X);
  loadA(1, Y);
  asm volatile("s_waitcnt vmcnt(8)" ::: "memory");   // stageX(0) done; A-loads fly
  __builtin_amdgcn_s_barrier();
  asm volatile("" ::: "memory");

  for (int c = 0; c < 8; ++c) {
    const char* xb = smem + (c & 1) * 26112;
    short8 Bp[4], Bq[4];                     // cross-tap B reg dbuf (chunk-local)
    loadB(xb, 0, Bp);                        // one exposed B latency per chunk
#pragma unroll
    for (int t = 0; t < 9; ++t) {
      int ct = c * 9 + t;
      short8 (&curA)[4] = (t % 3 == 0) ? X : ((t % 3 == 1) ? Y : Z);   // static
      short8 (&nxtA)[4] = (t % 3 == 0) ? Z : ((t % 3 == 1) ? X : Y);   // (t+2)%3
      short8 (&curB)[4] = (t & 1) ? Bq : Bp;
      short8 (&nxtB)[4] = (t & 1) ? Bp : Bq;
      if (ct < 70) loadA(ct + 2, nxtA);      // depth-2 global prefetch (stays in flight)
      if (t == 4 && c < 7)
        stageX(c + 1, (c + 1) & 1);          // mid-chunk issue: newer than all A(t<=6)
      __builtin_amdgcn_s_barrier();          // phase-align the 8 waves (no drain)
      asm volatile("s_waitcnt lgkmcnt(0)" ::: "memory");
      __builtin_amdgcn_sched_barrier(0);     // rule #18: MFMA must not hoist past wait
      if (t < 8) loadB(xb, t + 1, nxtB);     // issue B(t+1); hides under MFMA cluster
      __builtin_amdgcn_s_setprio(1);
#pragma unroll
      for (int nj = 0; nj < 4; ++nj)
#pragma unroll
        for (int mi = 0; mi < 4; ++mi)
          acc[mi][nj] = __builtin_amdgcn_mfma_f32_16x16x32_bf16(curA[mi], curB[nj], acc[mi][nj], 0, 0, 0);
      __builtin_amdgcn_s_setprio(0);
    }
    if (c < 7) {
      // counted drain: stageX(c+1) done; 8 newest vmem (A prefetches) in flight.
      asm volatile("s_waitcnt vmcnt(8) lgkmcnt(0)" ::: "memory");
      __builtin_amdgcn_s_barrier();
      asm volatile("" ::: "memory");
    }
  }
  __syncthreads();                  // full drain before smem reuse

  // ---- K-split reduction (kp1 -> LDS -> kp0) ----
#pragma unroll
  for (int p = 0; p < 2; ++p) {
    if (kp == 1 && wr == p) {
#pragma unroll
      for (int mi = 0; mi < 4; ++mi)
#pragma unroll
        for (int nj = 0; nj < 4; ++nj)
          *reinterpret_cast<f32x4*>(smem + wc * 16384 + (mi * 4 + nj) * 1024 + lane * 16) = acc[mi][nj];
    }
    __syncthreads();
    if (kp == 0 && wr == p) {
#pragma unroll
      for (int mi = 0; mi < 4; ++mi)
#pragma unroll
        for (int nj = 0; nj < 4; ++nj) {
          f32x4 v = *reinterpret_cast<const f32x4*>(smem + wc * 16384 + (mi * 4 + nj) * 1024 + lane * 16);
          acc[mi][nj] = acc[mi][nj] + v;
        }
    }
    __syncthreads();
  }

  // ---- epilogue: demod + bias, fp32 NCHW store ----
  if (kp == 0) {
    const float* rcpb = rcp + b * 512;
#pragma unroll
    for (int mi = 0; mi < 4; ++mi) {
      int ob = cog * 128 + wr * 64 + mi * 16 + l4 * 4;
      float rc[4], bi[4];
#pragma unroll
      for (int jj = 0; jj < 4; ++jj) { rc[jj] = rcpb[ob + jj]; bi[jj] = bias[ob + jj]; }
#pragma unroll
      for (int nj = 0; nj < 4; ++nj) {
        int row4 = wc * 2 + (nj >> 1);
        int wcol = (nj & 1) * 16 + l15;
        int h = hg * 4 + row4;
#pragma unroll
        for (int jj = 0; jj < 4; ++jj)
          out[(((size_t)b * 512 + ob + jj) * 32 + h) * 32 + wcol] = acc[mi][nj][jj] * rc[jj] + bi[jj];
      }
    }
  }
}

extern "C" void kernel_launch(void* const* d_in, const int* in_sizes, int n_in,
                              void* d_out, int out_size, void* d_ws, size_t ws_size,
                              hipStream_t stream) {
  const float* x    = (const float*)d_in[0];
  const float* ys   = (const float*)d_in[1];
  const float* w    = (const float*)d_in[2];
  const float* bias = (const float*)d_in[3];
  float* out = (float*)d_out;
  char* ws = (char*)d_ws;
  float* rcp = (float*)(ws + RCP_OFF);
  unsigned short* wpre = (unsigned short*)(ws + WPRE_OFF);
  unsigned short* xm   = (unsigned short*)(ws + XM_OFF);

  prep_kernel<<<768, 256, 0, stream>>>(x, ys, w, xm, wpre, rcp);
  conv_main<<<256, 512, 0, stream>>>(wpre, xm, rcp, bias, out);
}